// Round 1
// baseline (299.160 us; speedup 1.0000x reference)
//
#include <hip/hip_runtime.h>
#include <math.h>

#define GAT_ALPHA 0.2f

typedef float f32x4 __attribute__((ext_vector_type(4)));

__device__ __forceinline__ float lrelu_exp(float x) {
    float e = (x > 0.0f) ? x : (GAT_ALPHA * x);
    return __expf(e);   // exp(-2e29) underflows to exactly 0 for masked entries
}

// ---------------------------------------------------------------------------
// Prep: Wh = h@W (K=128), s1 = adj@a[:64], s2m = mask(adj)? adj@a[64:] : -1e30
// grid 256 blocks x 256 thr; warp w of block b handles row i = b*4+w, f = lane
// ---------------------------------------------------------------------------
__global__ __launch_bounds__(256) void gat_prep(
    const float* __restrict__ h, const float* __restrict__ adj,
    const float* __restrict__ W, const float* __restrict__ a,
    float* __restrict__ Wh, float* __restrict__ s1, float* __restrict__ s2m)
{
    const int t = threadIdx.x;
    const int f = t & 63;
    const int i = (blockIdx.x << 2) + (t >> 6);

    const float* __restrict__ hrow = h + i * 128;
    const float* __restrict__ arow = adj + i * 64;

    float wh = 0.0f;
    #pragma unroll 8
    for (int k = 0; k < 128; ++k) wh = fmaf(hrow[k], W[k * 64 + f], wh);
    Wh[i * 64 + f] = wh;

    float v1 = 0.0f, v2 = 0.0f;
    #pragma unroll 8
    for (int k = 0; k < 64; ++k) {
        const float av = arow[k];
        v1 = fmaf(av, a[k * 64 + f], v1);
        v2 = fmaf(av, a[(64 + k) * 64 + f], v2);
    }
    s1[i * 64 + f] = v1;
    // mask on source node j (dim 1 of att) uses adj[j, f] > 0
    s2m[i * 64 + f] = (arow[f] > 0.0f) ? v2 : -1e30f;
}

// ---------------------------------------------------------------------------
// Main: one block per destination row i. 256 thr: fg = t&15 (f4 = fg*4),
// jo = t>>4 (16 j-offsets). Pass 1: Z[f] = sum_j exp(lrelu(s1+s2m)).
// Pass 2: write attention (nontemporal, coalesced 4KiB/block-iter) and
// accumulate h_prime[f] = sum_j att * Wh[j,f]. No max-subtraction needed:
// values are O(+-10), masked lanes are exactly 0 either way.
// ---------------------------------------------------------------------------
__global__ __launch_bounds__(256) void gat_attn(
    const float* __restrict__ s1g, const float* __restrict__ s2m,
    const float* __restrict__ Wh,
    float* __restrict__ out_hp, float* __restrict__ out_att)
{
    __shared__ float red[16][64];
    __shared__ float zinv[64];

    const int t  = threadIdx.x;
    const int fg = t & 15;
    const int jo = t >> 4;
    const int i  = blockIdx.x;
    const int fb = fg << 2;

    const f32x4 s1v = *reinterpret_cast<const f32x4*>(s1g + i * 64 + fb);

    // ---- pass 1: partial Z over j = jo, jo+16, ... ----
    float z0 = 0.f, z1 = 0.f, z2 = 0.f, z3 = 0.f;
    #pragma unroll 2
    for (int jb = 0; jb < 1024; jb += 16) {
        const int j = jb + jo;
        const f32x4 sv = *reinterpret_cast<const f32x4*>(s2m + j * 64 + fb);
        z0 += lrelu_exp(s1v.x + sv.x);
        z1 += lrelu_exp(s1v.y + sv.y);
        z2 += lrelu_exp(s1v.z + sv.z);
        z3 += lrelu_exp(s1v.w + sv.w);
    }
    {
        f32x4 zp; zp.x = z0; zp.y = z1; zp.z = z2; zp.w = z3;
        *reinterpret_cast<f32x4*>(&red[jo][fb]) = zp;
    }
    __syncthreads();
    if (t < 64) {
        float z = 0.0f;
        #pragma unroll
        for (int o = 0; o < 16; ++o) z += red[o][t];
        zinv[t] = 1.0f / z;
    }
    __syncthreads();
    const f32x4 iv = *reinterpret_cast<const f32x4*>(&zinv[fb]);

    // ---- pass 2: normalize, stream out, accumulate h_prime ----
    float h0 = 0.f, h1 = 0.f, h2 = 0.f, h3 = 0.f;
    float* __restrict__ arow_out = out_att + (size_t)i * 65536;
    #pragma unroll 2
    for (int jb = 0; jb < 1024; jb += 16) {
        const int j = jb + jo;
        const f32x4 sv = *reinterpret_cast<const f32x4*>(s2m + j * 64 + fb);
        const f32x4 wv = *reinterpret_cast<const f32x4*>(Wh + j * 64 + fb);
        f32x4 o;
        o.x = lrelu_exp(s1v.x + sv.x) * iv.x;
        o.y = lrelu_exp(s1v.y + sv.y) * iv.y;
        o.z = lrelu_exp(s1v.z + sv.z) * iv.z;
        o.w = lrelu_exp(s1v.w + sv.w) * iv.w;
        h0 = fmaf(o.x, wv.x, h0);
        h1 = fmaf(o.y, wv.y, h1);
        h2 = fmaf(o.z, wv.z, h2);
        h3 = fmaf(o.w, wv.w, h3);
        __builtin_nontemporal_store(o, reinterpret_cast<f32x4*>(arow_out + j * 64 + fb));
    }

    // ---- h_prime reduce + ELU ----
    {
        f32x4 hp; hp.x = h0; hp.y = h1; hp.z = h2; hp.w = h3;
        *reinterpret_cast<f32x4*>(&red[jo][fb]) = hp;   // safe: no reader of red
    }                                                   // since last barrier
    __syncthreads();
    if (t < 64) {
        float v = 0.0f;
        #pragma unroll
        for (int o = 0; o < 16; ++o) v += red[o][t];
        out_hp[i * 64 + t] = (v > 0.0f) ? v : expm1f(v);
    }
}

extern "C" void kernel_launch(void* const* d_in, const int* in_sizes, int n_in,
                              void* d_out, int out_size, void* d_ws, size_t ws_size,
                              hipStream_t stream) {
    const float* h   = (const float*)d_in[0];   // (1024, 128)
    const float* adj = (const float*)d_in[1];   // (1024, 64)
    const float* W   = (const float*)d_in[2];   // (128, 64)
    const float* a   = (const float*)d_in[3];   // (128, 64)

    float* ws  = (float*)d_ws;                  // 768 KiB scratch used
    float* Wh  = ws;                            // (1024, 64)
    float* s1  = ws + 65536;                    // (1024, 64)
    float* s2m = ws + 131072;                   // (1024, 64) masked

    float* out     = (float*)d_out;
    float* out_hp  = out;                       // elu(h_prime): 65536 floats
    float* out_att = out + 65536;               // attention: 1024*1024*64

    gat_prep<<<256, 256, 0, stream>>>(h, adj, W, a, Wh, s1, s2m);
    gat_attn<<<1024, 256, 0, stream>>>(s1, s2m, Wh, out_hp, out_att);
}